// Round 12
// baseline (130.821 us; speedup 1.0000x reference)
//
#include <hip/hip_runtime.h>
#include <stdint.h>

#define T_ 256
#define B_ 8
#define E_ 512
#define H_ 32
#define HD_ 16
#define EXP_ 512
#define S_ 768          // T_ + EXP_
#define M_ 2048         // T_ * B_
#define SMOOTH_ 20.0f
#define PSTR 40         // P-tile LDS row stride (bf16)
#define VSTR 800        // V^T LDS row stride (bf16)
#define OSTR 20         // O-combine LDS row stride (f32)
#define LOG2E_ 1.44269504f
#define MB0_  (-100.988655f)   // -70 * log2e

typedef __attribute__((ext_vector_type(8)))  short bf16x8;
typedef __attribute__((ext_vector_type(4)))  float f32x4;
typedef __attribute__((ext_vector_type(16))) float f32x16;

// round-half-up pack: two fp32 -> dword of two bf16 (lo=a, hi=b)
__device__ __forceinline__ unsigned int pku(float a, float b)
{
    return ((__float_as_uint(a) + 0x8000u) >> 16) |
           ((__float_as_uint(b) + 0x8000u) & 0xFFFF0000u);
}
__device__ __forceinline__ ushort bf1(float a)   // RNE (epilogue only)
{
    unsigned int u = __float_as_uint(a);
    u = u + 0x7FFFu + ((u >> 16) & 1u);
    return (ushort)(u >> 16);
}

union U16 { uint4 u; bf16x8 v; };

// ---------------------------------------------------------------------------
// Templated bf16 MFMA GEMM body with prefetch. AF/BF: operand source is fp32
// (convert during LDS staging) vs bf16 (pure copy). steps are in source
// elements per 64-k tile.
// ---------------------------------------------------------------------------
template<bool AF, bool BF>
__device__ __forceinline__ void gemm_body(const void* __restrict__ Xp, int xstep,
                                          const void* __restrict__ Wp, int wstep,
                                          f32x4 acc[2][2],
                                          ushort* As, ushort* Bs)
{
    const int tid  = threadIdx.x;
    const int lrow = tid >> 2;
    const int kq   = tid & 3;
    const int l    = tid & 63;
    const int w    = tid >> 6;
    const int wm   = w & 1;
    const int wn   = w >> 1;
    const int lq   = l >> 4;
    const int ln   = l & 15;

    ushort* Aw = &As[lrow * 72 + kq * 16];
    ushort* Bw = &Bs[lrow * 72 + kq * 16];

    const float*  Xf = (const float*)Xp;
    const ushort* Xh = (const ushort*)Xp;
    const float*  Wf = (const float*)Wp;
    const ushort* Wh = (const ushort*)Wp;

    float4 fa0, fa1, fa2, fa3, fb0, fb1, fb2, fb3;
    uint4  ha0, ha1, hb0, hb1;

    if (AF) {
        fa0 = *(const float4*)&Xf[0];  fa1 = *(const float4*)&Xf[4];
        fa2 = *(const float4*)&Xf[8];  fa3 = *(const float4*)&Xf[12];
    } else {
        ha0 = *(const uint4*)&Xh[0];   ha1 = *(const uint4*)&Xh[8];
    }
    if (BF) {
        fb0 = *(const float4*)&Wf[0];  fb1 = *(const float4*)&Wf[4];
        fb2 = *(const float4*)&Wf[8];  fb3 = *(const float4*)&Wf[12];
    } else {
        hb0 = *(const uint4*)&Wh[0];   hb1 = *(const uint4*)&Wh[8];
    }

    for (int it = 0; it < E_ / 64; ++it) {
        __syncthreads();
        if (AF) {
            *(uint4*)&Aw[0] = make_uint4(pku(fa0.x, fa0.y), pku(fa0.z, fa0.w),
                                         pku(fa1.x, fa1.y), pku(fa1.z, fa1.w));
            *(uint4*)&Aw[8] = make_uint4(pku(fa2.x, fa2.y), pku(fa2.z, fa2.w),
                                         pku(fa3.x, fa3.y), pku(fa3.z, fa3.w));
        } else {
            *(uint4*)&Aw[0] = ha0;
            *(uint4*)&Aw[8] = ha1;
        }
        if (BF) {
            *(uint4*)&Bw[0] = make_uint4(pku(fb0.x, fb0.y), pku(fb0.z, fb0.w),
                                         pku(fb1.x, fb1.y), pku(fb1.z, fb1.w));
            *(uint4*)&Bw[8] = make_uint4(pku(fb2.x, fb2.y), pku(fb2.z, fb2.w),
                                         pku(fb3.x, fb3.y), pku(fb3.z, fb3.w));
        } else {
            *(uint4*)&Bw[0] = hb0;
            *(uint4*)&Bw[8] = hb1;
        }
        __syncthreads();
        if (it < E_ / 64 - 1) {
            if (AF) {
                Xf += xstep;
                fa0 = *(const float4*)&Xf[0];  fa1 = *(const float4*)&Xf[4];
                fa2 = *(const float4*)&Xf[8];  fa3 = *(const float4*)&Xf[12];
            } else {
                Xh += xstep;
                ha0 = *(const uint4*)&Xh[0];   ha1 = *(const uint4*)&Xh[8];
            }
            if (BF) {
                Wf += wstep;
                fb0 = *(const float4*)&Wf[0];  fb1 = *(const float4*)&Wf[4];
                fb2 = *(const float4*)&Wf[8];  fb3 = *(const float4*)&Wf[12];
            } else {
                Wh += wstep;
                hb0 = *(const uint4*)&Wh[0];   hb1 = *(const uint4*)&Wh[8];
            }
        }
#pragma unroll
        for (int kb = 0; kb < 2; ++kb) {
            bf16x8 af0 = *(const bf16x8*)&As[(32 * wm + ln) * 72 + 32 * kb + lq * 8];
            bf16x8 af1 = *(const bf16x8*)&As[(32 * wm + 16 + ln) * 72 + 32 * kb + lq * 8];
            bf16x8 bf0 = *(const bf16x8*)&Bs[(32 * wn + ln) * 72 + 32 * kb + lq * 8];
            bf16x8 bf1 = *(const bf16x8*)&Bs[(32 * wn + 16 + ln) * 72 + 32 * kb + lq * 8];
            acc[0][0] = __builtin_amdgcn_mfma_f32_16x16x32_bf16(af0, bf0, acc[0][0], 0, 0, 0);
            acc[0][1] = __builtin_amdgcn_mfma_f32_16x16x32_bf16(af0, bf1, acc[0][1], 0, 0, 0);
            acc[1][0] = __builtin_amdgcn_mfma_f32_16x16x32_bf16(af1, bf0, acc[1][0], 0, 0, 0);
            acc[1][1] = __builtin_amdgcn_mfma_f32_16x16x32_bf16(af1, bf1, acc[1][1], 0, 0, 0);
        }
    }
}

// ---------------------------------------------------------------------------
// qkv GEMM: X fp32, W(z) fp32, conversion fused into staging.
// ---------------------------------------------------------------------------
__global__ __launch_bounds__(256)
void qkv_gemm(const float* __restrict__ X,
              const float* __restrict__ Wq, const float* __restrict__ Wk,
              const float* __restrict__ Wv,
              const float* __restrict__ bq, const float* __restrict__ bv,
              ushort* __restrict__ Qb, ushort* __restrict__ Kb,
              ushort* __restrict__ Vb)
{
    __shared__ __align__(16) ushort AsBs[2 * 64 * 72];
    ushort* As = AsBs;
    ushort* Bs = AsBs + 64 * 72;

    const int z = blockIdx.z;
    const float* W     = (z == 0) ? Wq : (z == 1 ? Wk : Wv);
    const float* bias  = (z == 0) ? bq : (z == 2 ? bv : nullptr);
    ushort* dst        = (z == 0) ? Qb : (z == 1 ? Kb : Vb);

    const int m0 = blockIdx.y * 64;
    const int n0 = blockIdx.x * 64;

    f32x4 acc[2][2];
#pragma unroll
    for (int i = 0; i < 2; ++i)
#pragma unroll
        for (int j = 0; j < 2; ++j)
            acc[i][j] = (f32x4){0.f, 0.f, 0.f, 0.f};

    const int tid  = threadIdx.x;
    const int lrow = tid >> 2;
    const int kq   = tid & 3;
    gemm_body<true, true>(&X[(size_t)(m0 + lrow) * E_ + kq * 16], 64,
                          &W[(size_t)(n0 + lrow) * E_ + kq * 16], 64,
                          acc, As, Bs);

    const int l  = tid & 63;
    const int w  = tid >> 6;
    const int wm = w & 1;
    const int wn = w >> 1;
    const int lq = l >> 4;
    const int ln = l & 15;

    const float b0_ = bias ? bias[n0 + 32 * wn + ln]      : 0.f;
    const float b1_ = bias ? bias[n0 + 32 * wn + 16 + ln] : 0.f;

    __syncthreads();
    ushort* Ls = As;
#pragma unroll
    for (int j = 0; j < 2; ++j) {
        const float bb = j ? b1_ : b0_;
#pragma unroll
        for (int i = 0; i < 2; ++i)
#pragma unroll
            for (int r = 0; r < 4; ++r)
                Ls[(32 * wm + 16 * i + lq * 4 + r) * 72 + 32 * wn + 16 * j + ln] =
                    bf1(acc[i][j][r] + bb);
    }
    __syncthreads();

    {
        const int lm = tid & 63;
        const int hh = tid >> 6;
        uint4 f0 = *(const uint4*)&Ls[lm * 72 + hh * 16];
        uint4 f1 = *(const uint4*)&Ls[lm * 72 + hh * 16 + 8];
        const int m = m0 + lm;
        const int t = m >> 3;
        const int b = m & 7;
        const int h = (n0 >> 4) + hh;
        ushort* dp = &dst[(((size_t)(b * H_ + h)) * T_ + t) * HD_];
        *(uint4*)&dp[0] = f0;
        *(uint4*)&dp[8] = f1;
    }
}

// ---------------------------------------------------------------------------
// out GEMM: A = Ab bf16 [b][h][t][16]; B = Wo fp32 (fused convert).
// ---------------------------------------------------------------------------
__global__ __launch_bounds__(256)
void out_gemm(const ushort* __restrict__ Ab, const float* __restrict__ Wo,
              const float* __restrict__ bo, float* __restrict__ dst)
{
    __shared__ __align__(16) ushort AsBs[2 * 64 * 72];
    ushort* As = AsBs;
    ushort* Bs = AsBs + 64 * 72;

    const int m0 = blockIdx.y * 64;
    const int n0 = blockIdx.x * 64;

    f32x4 acc[2][2];
#pragma unroll
    for (int i = 0; i < 2; ++i)
#pragma unroll
        for (int j = 0; j < 2; ++j)
            acc[i][j] = (f32x4){0.f, 0.f, 0.f, 0.f};

    const int tid  = threadIdx.x;
    const int lrow = tid >> 2;
    const int kq   = tid & 3;
    const int m    = m0 + lrow;
    const int t    = m >> 3;
    const int b    = m & 7;
    gemm_body<false, true>(&Ab[(((size_t)(b * H_ + kq)) * T_ + t) * HD_], 4 * T_ * HD_,
                           &Wo[(size_t)(n0 + lrow) * E_ + kq * 16], 64,
                           acc, As, Bs);

    const int l  = tid & 63;
    const int w  = tid >> 6;
    const int wm = w & 1;
    const int wn = w >> 1;
    const int lq = l >> 4;
    const int ln = l & 15;

    const float bo0 = bo[n0 + 32 * wn + ln];
    const float bo1 = bo[n0 + 32 * wn + 16 + ln];

    __syncthreads();
    float* Lf = (float*)AsBs;
#pragma unroll
    for (int j = 0; j < 2; ++j) {
        const float bb = j ? bo1 : bo0;
#pragma unroll
        for (int i = 0; i < 2; ++i)
#pragma unroll
            for (int r = 0; r < 4; ++r)
                Lf[(32 * wm + 16 * i + lq * 4 + r) * 68 + 32 * wn + 16 * j + ln] =
                    acc[i][j][r] + bb;
    }
    __syncthreads();

    {
        const int lm = tid & 63;
        const int hh = tid >> 6;
        float* dp = &dst[(size_t)(m0 + lm) * E_ + n0 + hh * 16];
#pragma unroll
        for (int c = 0; c < 4; ++c) {
            float4 v = *(const float4*)&Lf[lm * 68 + hh * 16 + c * 4];
            *(float4*)&dp[c * 4] = v;
        }
    }
}

__device__ __forceinline__ void scat8(ushort* d, uint4 u)
{
    d[0 * VSTR] = (ushort)(u.x);  d[1 * VSTR] = (ushort)(u.x >> 16);
    d[2 * VSTR] = (ushort)(u.y);  d[3 * VSTR] = (ushort)(u.y >> 16);
    d[4 * VSTR] = (ushort)(u.z);  d[5 * VSTR] = (ushort)(u.z >> 16);
    d[6 * VSTR] = (ushort)(u.w);  d[7 * VSTR] = (ushort)(u.w >> 16);
}

// ---------------------------------------------------------------------------
// Attention v9: s-on-lanes scores + re-algebrized softmax:
//   msf[s] = -70*log2e + (masked ? -1e5 : 0)   (additive mask)
//   lwK = lw*log2e; arg = fma(sc, lwK, fma(lwK, 20, mb));
//   e = exp2(arg) via __builtin_amdgcn_exp2f; z += e; p = e*lw; half-up pack.
// ---------------------------------------------------------------------------
__global__ __launch_bounds__(512)
void attn_kernel(const ushort* __restrict__ Qb, const ushort* __restrict__ Kb,
                 const ushort* __restrict__ Vb, const float* __restrict__ LAW,
                 const int* __restrict__ kpm, const int* __restrict__ em,
                 const int* __restrict__ oc, ushort* __restrict__ Ab)
{
    __shared__ __align__(16) ushort Ks[S_ * HD_];
    __shared__ __align__(16) ushort Vt[HD_ * VSTR];
    __shared__ __align__(16) float  msf[S_];
    __shared__ __align__(16) ushort Pb[8][32 * PSTR];
    __shared__ __align__(16) float  Zpart[2][128];

    float*  Obuf = (float*)Ks;        // alias after loop
    ushort* Ob   = (ushort*)Vt;       // alias after loop

    const int tid    = threadIdx.x;
    const int blk    = blockIdx.x;
    const int bh     = blk >> 1;
    const int thalf  = blk & 1;
    const int b      = bh >> 5;
    const int h      = bh & 31;

    ((uint4*)Ks)[tid] = ((const uint4*)&Kb[(size_t)bh * T_ * HD_])[tid];
    {
        const int t    = tid >> 1;
        const int half = tid & 1;
        uint4 v = *(const uint4*)&Vb[((size_t)bh * T_ + t) * HD_ + half * 8];
        scat8(&Vt[half * 8 * VSTR + t], v);
    }
    {
        const int j   = tid;
        const int src = oc[b * EXP_ + j];
        const uint4* kr = (const uint4*)&Kb[((size_t)bh * T_ + src) * HD_];
        *(uint4*)&Ks[(T_ + j) * HD_ + 0] = kr[0];
        *(uint4*)&Ks[(T_ + j) * HD_ + 8] = kr[1];
        const uint4* vr = (const uint4*)&Vb[((size_t)bh * T_ + src) * HD_];
        scat8(&Vt[T_ + j], vr[0]);
        scat8(&Vt[8 * VSTR + T_ + j], vr[1]);
    }
    {
        const int s = tid;
        const int m = (s < T_) ? kpm[b * T_ + s] : em[b * EXP_ + (s - T_)];
        msf[s] = m ? -1.0e5f : MB0_;
        if (tid < 256) {
            const int s2 = 512 + tid;
            msf[s2] = em[b * EXP_ + (s2 - T_)] ? -1.0e5f : MB0_;
        }
    }

    const int w      = tid >> 6;
    const int l      = tid & 63;
    const int slane  = l & 31;
    const int khalf  = l >> 5;
    const int wt     = w & 3;
    const int sh     = w >> 2;
    const int tbase  = thalf * 128 + wt * 32;
    bf16x8 qf = *(const bf16x8*)&Qb[((size_t)bh * T_ + tbase + slane) * HD_ + khalf * 8];

    __syncthreads();

    const f32x16 zero16 = {0.f,0.f,0.f,0.f,0.f,0.f,0.f,0.f,
                           0.f,0.f,0.f,0.f,0.f,0.f,0.f,0.f};
    f32x4 o0 = {0.f, 0.f, 0.f, 0.f};
    f32x4 o1 = {0.f, 0.f, 0.f, 0.f};
    float zacc[16];
#pragma unroll
    for (int r = 0; r < 16; ++r) zacc[r] = 0.f;

    const float* lawb = &LAW[((size_t)b * T_ + tbase + khalf * 4) * S_ + slane];
    ushort* pw = &Pb[w][slane];
    const int tl = l & 15;
    const int kg = l >> 4;

    for (int i = sh * 12; i < sh * 12 + 12; ++i) {
        bf16x8 kf = *(const bf16x8*)&Ks[(i * 32 + slane) * HD_ + khalf * 8];

        float lw[16];
        const float* lp = lawb + i * 32;
#pragma unroll
        for (int r = 0; r < 16; ++r)
            lw[r] = lp[(size_t)((r & 3) + 8 * (r >> 2)) * S_];

        f32x16 sc = __builtin_amdgcn_mfma_f32_32x32x16_bf16(qf, kf, zero16, 0, 0, 0);
        const float mb = msf[i * 32 + slane];

#pragma unroll
        for (int r = 0; r < 16; ++r) {
            const float lwK = lw[r] * LOG2E_;
            const float arg = __builtin_fmaf(sc[r], lwK,
                              __builtin_fmaf(lwK, SMOOTH_, mb));
            const float e = __builtin_amdgcn_exp2f(arg);
            zacc[r] += e;
            const float p = e * lw[r];
            pw[((r & 3) + 8 * (r >> 2) + 4 * khalf) * PSTR] =
                (ushort)((__float_as_uint(p) + 0x8000u) >> 16);
        }

        bf16x8 vf = *(const bf16x8*)&Vt[tl * VSTR + i * 32 + kg * 8];
        {
            const ushort* pr0 = &Pb[w][(0 * 16 + tl) * PSTR + kg * 8];
            U16 u;
            uint2 a0 = *(const uint2*)pr0;
            uint2 a1 = *(const uint2*)(pr0 + 4);
            u.u = make_uint4(a0.x, a0.y, a1.x, a1.y);
            o0 = __builtin_amdgcn_mfma_f32_16x16x32_bf16(vf, u.v, o0, 0, 0, 0);
            const ushort* pr1 = &Pb[w][(1 * 16 + tl) * PSTR + kg * 8];
            uint2 b0 = *(const uint2*)pr1;
            uint2 b1 = *(const uint2*)(pr1 + 4);
            u.u = make_uint4(b0.x, b0.y, b1.x, b1.y);
            o1 = __builtin_amdgcn_mfma_f32_16x16x32_bf16(vf, u.v, o1, 0, 0, 0);
        }
    }

#pragma unroll
    for (int m = 1; m < 32; m <<= 1) {
#pragma unroll
        for (int r = 0; r < 16; ++r)
            zacc[r] += __shfl_xor(zacc[r], m);
    }

    __syncthreads();

    if (l == 0 || l == 32) {
#pragma unroll
        for (int r = 0; r < 16; ++r)
            Zpart[sh][wt * 32 + (r & 3) + 8 * (r >> 2) + 4 * khalf] = zacc[r];
    }
    if (sh == 1) {
#pragma unroll
        for (int th = 0; th < 2; ++th) {
            const f32x4 o = th ? o1 : o0;
            *(float4*)&Obuf[((wt * 2 + th) * 16 + tl) * OSTR + kg * 4] =
                make_float4(o[0], o[1], o[2], o[3]);
        }
    }
    __syncthreads();

    if (sh == 0) {
#pragma unroll
        for (int th = 0; th < 2; ++th) {
            const int trow = wt * 32 + th * 16 + tl;
            const float Zt  = Zpart[0][trow] + Zpart[1][trow];
            const float inv = (Zt > 0.f) ? 1.f / Zt : 0.f;
            float4 po = *(const float4*)&Obuf[((wt * 2 + th) * 16 + tl) * OSTR + kg * 4];
            const f32x4 o = th ? o1 : o0;
            float ov[4] = {(o[0] + po.x) * inv, (o[1] + po.y) * inv,
                           (o[2] + po.z) * inv, (o[3] + po.w) * inv};
            *(uint*)&Ob[trow * 16 + kg * 4]     = pku(ov[0], ov[1]);
            *(uint*)&Ob[trow * 16 + kg * 4 + 2] = pku(ov[2], ov[3]);
        }
    }
    __syncthreads();

    if (tid < 256) {
        ushort* dp = &Ab[(((size_t)(b * H_ + h)) * T_ + thalf * 128) * HD_];
        *(uint4*)&dp[tid * 8] = *(const uint4*)&Ob[tid * 8];
    }
}

// ---------------------------------------------------------------------------
extern "C" void kernel_launch(void* const* d_in, const int* in_sizes, int n_in,
                              void* d_out, int out_size, void* d_ws, size_t ws_size,
                              hipStream_t stream)
{
    const float* query = (const float*)d_in[0];
    const int*   oc    = (const int*)d_in[1];
    const int*   em    = (const int*)d_in[2];
    const int*   kpm   = (const int*)d_in[3];
    const float* law   = (const float*)d_in[4];
    const float* Wq    = (const float*)d_in[5];
    const float* bq    = (const float*)d_in[6];
    const float* Wk    = (const float*)d_in[7];
    const float* Wv    = (const float*)d_in[8];
    const float* bv    = (const float*)d_in[9];
    const float* Wo    = (const float*)d_in[10];
    const float* bo    = (const float*)d_in[11];
    float* out = (float*)d_out;

    ushort* Qb = (ushort*)d_ws;                  // [bh][t][16]
    ushort* Kb = Qb + (size_t)1048576;           // [bh][t][16]
    ushort* Vb = Kb + (size_t)1048576;           // [bh][t][16]
    ushort* Ab = Vb + (size_t)1048576;           // [b][h][t][16]

    dim3 gq(E_ / 64, M_ / 64, 3);
    qkv_gemm<<<gq, 256, 0, stream>>>(query, Wq, Wk, Wv, bq, bv, Qb, Kb, Vb);

    attn_kernel<<<B_ * H_ * 2, 512, 0, stream>>>(Qb, Kb, Vb, law, kpm, em, oc, Ab);

    dim3 go(E_ / 64, M_ / 64, 1);
    out_gemm<<<go, 256, 0, stream>>>(Ab, Wo, bo, out);
}